// Round 3
// baseline (457.913 us; speedup 1.0000x reference)
//
#include <hip/hip_runtime.h>

typedef short bf16x8 __attribute__((ext_vector_type(8)));
typedef float f32x4  __attribute__((ext_vector_type(4)));
typedef unsigned int u32x2 __attribute__((ext_vector_type(2)));

#define B_SZ   2
#define T_SZ   2048
#define N_SZ   2048
#define HID_SZ 1024
#define NHEADS 16

// scale/sqrt(half) * log2(e), folded into Q at projection epilogue
#define SLOG2E 0.25500297f

#define EXP2(x) exp2f(x)

static __device__ __forceinline__ short f2bf(float f) {
    unsigned u = __float_as_uint(f);
    u = (u + 0x7fffu + ((u >> 16) & 1u)) >> 16;   // RNE
    return (short)u;
}

// pack two floats -> two bf16 (round-half-up; 1-ulp-tie diff vs RNE)
static __device__ __forceinline__ unsigned pk2(float a, float b) {
    unsigned ua = (__float_as_uint(a) + 0x8000u) >> 16;
    unsigned ub = (__float_as_uint(b) + 0x8000u) & 0xffff0000u;
    return ua | ub;
}

union U8 { bf16x8 h; unsigned u[4]; };

static __device__ __forceinline__ bf16x8 mk_frag(float4 a, float4 b) {
    U8 r;
    r.u[0] = pk2(a.x, a.y); r.u[1] = pk2(a.z, a.w);
    r.u[2] = pk2(b.x, b.y); r.u[3] = pk2(b.z, b.w);
    return r.h;
}

// async global->LDS, 16B per lane; LDS dest = wave-uniform base + lane*16
static __device__ __forceinline__ void gload16(const void* g, void* l) {
    __builtin_amdgcn_global_load_lds(
        (const __attribute__((address_space(1))) unsigned int*)g,
        (__attribute__((address_space(3))) unsigned int*)l, 16, 0, 0);
}

// ---------------------------------------------------------------------------
// Projection GEMM (m97-style): Y[m,c] = sum_k X[m,k]*W[c,k], fp32 in, bf16 out.
// 128x128 block tile, 256 thr = 4 waves (2x2), 64x64 per wave, BK=32.
// LDS layout (fp32): [kchunk 0..7][row 0..127][4 floats] — lane-order DMA
// contiguous per (chunk,half) instruction; fragment reads are 2-way (free).
// proj 0: q = (dec@Wq^T)*SLOG2E -> qbuf [4096,1024] bf16
// proj 1: k = enc@Wk^T          -> kbuf [4096,1024] bf16
// proj 2: v = enc@Wv^T          -> vT [B,H,64,2048] bf16, n-permuted per
//          64-block: n' = (n&~63) | ((n&15)*4 + ((n>>4)&3))   (matches attn P)
// ---------------------------------------------------------------------------
__global__ __launch_bounds__(256) void proj_kernel(
    const float* __restrict__ enc, const float* __restrict__ dec,
    const float* __restrict__ Wq, const float* __restrict__ Wk,
    const float* __restrict__ Wv,
    short* __restrict__ qbuf, short* __restrict__ kbuf, short* __restrict__ vT)
{
    const int proj = blockIdx.z;
    const float* __restrict__ X = (proj == 0) ? dec : enc;
    const float* __restrict__ W = (proj == 0) ? Wq : ((proj == 1) ? Wk : Wv);

    const int m0 = blockIdx.x * 128;
    const int c0 = blockIdx.y * 128;

    __shared__ float As[8 * 512];   // 16 KB
    __shared__ float Bs[8 * 512];   // 16 KB

    const int tid  = threadIdx.x;
    const int lane = tid & 63;
    const int w    = tid >> 6;
    const int wm   = (w >> 1) * 64;
    const int wn   = (w & 1) * 64;
    const int q4   = lane >> 4;
    const int r16  = lane & 15;

    f32x4 acc[4][4] = {};

    for (int k0 = 0; k0 < HID_SZ; k0 += 32) {
        __syncthreads();   // prev iter's ds_reads done before overwrite
#pragma unroll
        for (int j = 0; j < 4; ++j) {
            const int idx = w * 4 + j;        // 0..15
            const int c   = idx >> 1;         // kchunk 0..7
            const int hh  = idx & 1;          // row half
            const int row = hh * 64 + lane;
            const size_t goffA = (size_t)(m0 + row) * HID_SZ + k0 + c * 4;
            const size_t goffB = (size_t)(c0 + row) * HID_SZ + k0 + c * 4;
            float* ldsA = &As[c * 512 + hh * 256];
            float* ldsB = &Bs[c * 512 + hh * 256];
            gload16(&X[goffA], ldsA);
            gload16(&W[goffB], ldsB);
        }
        __syncthreads();   // drain staging

        bf16x8 af[4], bfr[4];
#pragma unroll
        for (int mi = 0; mi < 4; ++mi) {
            const int row = wm + mi * 16 + r16;
            const float* p = &As[(q4 * 2) * 512 + row * 4];
            af[mi] = mk_frag(*(const float4*)p, *(const float4*)(p + 512));
        }
#pragma unroll
        for (int ni = 0; ni < 4; ++ni) {
            const int row = wn + ni * 16 + r16;
            const float* p = &Bs[(q4 * 2) * 512 + row * 4];
            bfr[ni] = mk_frag(*(const float4*)p, *(const float4*)(p + 512));
        }
#pragma unroll
        for (int mi = 0; mi < 4; ++mi)
#pragma unroll
            for (int ni = 0; ni < 4; ++ni)
                acc[mi][ni] = __builtin_amdgcn_mfma_f32_16x16x32_bf16(
                    af[mi], bfr[ni], acc[mi][ni], 0, 0, 0);
    }

#pragma unroll
    for (int mi = 0; mi < 4; ++mi)
#pragma unroll
    for (int ni = 0; ni < 4; ++ni)
#pragma unroll
    for (int r = 0; r < 4; ++r) {
        const int m = m0 + wm + mi * 16 + q4 * 4 + r;
        const int c = c0 + wn + ni * 16 + r16;
        const float v = acc[mi][ni][r];
        if (proj == 0) {
            qbuf[(size_t)m * HID_SZ + c] = f2bf(v * SLOG2E);
        } else if (proj == 1) {
            kbuf[(size_t)m * HID_SZ + c] = f2bf(v);
        } else {
            const int bb = m >> 11, n = m & (N_SZ - 1);
            const int hh = c >> 6, d = c & 63;
            const int np = (n & ~63) | (((n & 15) << 2) | ((n >> 4) & 3));
            vT[((size_t)((bb * NHEADS + hh) * 64 + d)) * N_SZ + np] = f2bf(v);
        }
    }
}

// ---------------------------------------------------------------------------
// Flash-style differential cross-attention, software-pipelined:
//  - next-chunk K fragments prefetched into registers (cross-chunk)
//  - current-chunk V fragments issued at chunk top (used ~end of chunk)
//  - no-max softmax (Q pre-scaled into log2 domain), deferred l-reduction
//  - wave-private P in LDS, XOR-swizzled groups, NO barriers
// Grid: (T/64, NHEADS, B); 256 thr = 4 waves; wave w owns 16 t-rows.
// ---------------------------------------------------------------------------
__global__ __launch_bounds__(256) void attn_kernel(
    const short* __restrict__ qbuf, const short* __restrict__ kbuf,
    const short* __restrict__ vT,
    const float* __restrict__ lq1, const float* __restrict__ lq2,
    const float* __restrict__ lk1, const float* __restrict__ lk2,
    float* __restrict__ out)
{
    const int t0  = blockIdx.x * 64;
    const int h   = blockIdx.y;
    const int b   = blockIdx.z;
    const int tid = threadIdx.x;
    const int w    = tid >> 6;
    const int lane = tid & 63;
    const int q4   = lane >> 4;
    const int r16  = lane & 15;

    float d1 = 0.f, d2 = 0.f;
#pragma unroll
    for (int i = 0; i < 32; ++i) { d1 += lq1[i] * lk1[i]; d2 += lq2[i] * lk2[i]; }
    const float lam = __expf(d1) - __expf(d2) + 0.8f;

    __shared__ short Pl[4][2 * 16 * 64];
    short* __restrict__ P = &Pl[w][0];

    const int trow = t0 + w * 16 + r16;
    const short* qrow = qbuf + ((size_t)(b * T_SZ + trow)) * HID_SZ + h * 64;
    const bf16x8 aq1 = *(const bf16x8*)(qrow + q4 * 8);
    const bf16x8 aq2 = *(const bf16x8*)(qrow + 32 + q4 * 8);

    const short* kbase = kbuf + (size_t)b * N_SZ * HID_SZ + h * 64;
    const short* vbase = vT + ((size_t)(b * NHEADS + h)) * 64 * N_SZ;

    f32x4 o0[4] = {}, o1[4] = {};
    float l0p[4] = {0.f, 0.f, 0.f, 0.f}, l1p[4] = {0.f, 0.f, 0.f, 0.f};

    const int wg_half = (r16 >> 1);
    const int wlo     = (r16 & 1) * 4;

    // prefetch K chunk 0
    bf16x8 kc1[4], kc2[4];
#pragma unroll
    for (int s = 0; s < 4; ++s) {
        const short* krow = kbase + (size_t)(s * 16 + r16) * HID_SZ;
        kc1[s] = *(const bf16x8*)(krow + q4 * 8);
        kc2[s] = *(const bf16x8*)(krow + 32 + q4 * 8);
    }

    for (int n0 = 0; n0 < N_SZ; n0 += 64) {
        // issue current-chunk V loads (consumed at PV, ~end of chunk)
        bf16x8 vfr[2][4];
#pragma unroll
        for (int kk = 0; kk < 2; ++kk)
#pragma unroll
            for (int d = 0; d < 4; ++d)
                vfr[kk][d] = *(const bf16x8*)(vbase + (size_t)(d * 16 + r16) * N_SZ
                                              + n0 + kk * 32 + q4 * 8);

        // issue next-chunk K loads (consumed next iteration)
        bf16x8 kn1[4], kn2[4];
        const int n1 = (n0 + 64) & (N_SZ - 1);   // wrap: last-iter load harmless
#pragma unroll
        for (int s = 0; s < 4; ++s) {
            const short* krow = kbase + (size_t)(n1 + s * 16 + r16) * HID_SZ;
            kn1[s] = *(const bf16x8*)(krow + q4 * 8);
            kn2[s] = *(const bf16x8*)(krow + 32 + q4 * 8);
        }

        // QK on resident registers
        const f32x4 zz = {0.f, 0.f, 0.f, 0.f};
        f32x4 s0[4], s1[4];
#pragma unroll
        for (int s = 0; s < 4; ++s) {
            s0[s] = __builtin_amdgcn_mfma_f32_16x16x32_bf16(aq1, kc1[s], zz, 0, 0, 0);
            s1[s] = __builtin_amdgcn_mfma_f32_16x16x32_bf16(aq2, kc2[s], zz, 0, 0, 0);
        }

        // exp2 + pack + wave-private LDS stage
#pragma unroll
        for (int r = 0; r < 4; ++r) {
            const int row = q4 * 4 + r;
            const int wo  = row * 64 + ((wg_half ^ (row & 7)) << 3) + wlo;
            {
                float p0 = EXP2(s0[0][r]), p1 = EXP2(s0[1][r]);
                float p2 = EXP2(s0[2][r]), p3 = EXP2(s0[3][r]);
                l0p[r] += (p0 + p1) + (p2 + p3);
                u32x2 pw; pw[0] = pk2(p0, p1); pw[1] = pk2(p2, p3);
                *(u32x2*)&P[wo] = pw;
            }
            {
                float p0 = EXP2(s1[0][r]), p1 = EXP2(s1[1][r]);
                float p2 = EXP2(s1[2][r]), p3 = EXP2(s1[3][r]);
                l1p[r] += (p0 + p1) + (p2 + p3);
                u32x2 pw; pw[0] = pk2(p0, p1); pw[1] = pk2(p2, p3);
                *(u32x2*)&P[1024 + wo] = pw;
            }
        }

        // PV (P via LDS layout transform; V from prefetched regs)
#pragma unroll
        for (int kk = 0; kk < 2; ++kk) {
            const int ro = r16 * 64 + (((kk * 4 + q4) ^ (r16 & 7)) << 3);
            bf16x8 ap0 = *(const bf16x8*)&P[ro];
            bf16x8 ap1 = *(const bf16x8*)&P[1024 + ro];
#pragma unroll
            for (int d = 0; d < 4; ++d) {
                o0[d] = __builtin_amdgcn_mfma_f32_16x16x32_bf16(ap0, vfr[kk][d], o0[d], 0, 0, 0);
                o1[d] = __builtin_amdgcn_mfma_f32_16x16x32_bf16(ap1, vfr[kk][d], o1[d], 0, 0, 0);
            }
        }

        // rotate K prefetch
#pragma unroll
        for (int s = 0; s < 4; ++s) { kc1[s] = kn1[s]; kc2[s] = kn2[s]; }
    }

    // final l reduction across the 16 col-lanes — once
#pragma unroll
    for (int m = 1; m < 16; m <<= 1)
#pragma unroll
        for (int r = 0; r < 4; ++r) {
            l0p[r] += __shfl_xor(l0p[r], m);
            l1p[r] += __shfl_xor(l1p[r], m);
        }

    float rl0[4], rl1[4];
#pragma unroll
    for (int r = 0; r < 4; ++r) { rl0[r] = 1.f / l0p[r]; rl1[r] = lam / l1p[r]; }

#pragma unroll
    for (int d = 0; d < 4; ++d)
#pragma unroll
        for (int r = 0; r < 4; ++r) {
            const int t  = t0 + w * 16 + q4 * 4 + r;
            const int vd = d * 16 + r16;
            out[((size_t)(b * T_SZ + t)) * HID_SZ + h * 64 + vd] =
                o0[d][r] * rl0[r] - o1[d][r] * rl1[r];
        }
}

extern "C" void kernel_launch(void* const* d_in, const int* in_sizes, int n_in,
                              void* d_out, int out_size, void* d_ws, size_t ws_size,
                              hipStream_t stream)
{
    (void)in_sizes; (void)n_in; (void)out_size; (void)ws_size;

    const float* enc = (const float*)d_in[0];
    const float* dec = (const float*)d_in[1];
    const float* Wq  = (const float*)d_in[2];
    const float* Wk  = (const float*)d_in[3];
    const float* Wv  = (const float*)d_in[4];
    const float* lq1 = (const float*)d_in[5];
    const float* lq2 = (const float*)d_in[6];
    const float* lk1 = (const float*)d_in[7];
    const float* lk2 = (const float*)d_in[8];
    float* out = (float*)d_out;

    short* qbuf = (short*)d_ws;
    short* kbuf = qbuf + (size_t)4096 * 1024;
    short* vT   = kbuf + (size_t)4096 * 1024;

    dim3 pgrid(32, 8, 3);
    proj_kernel<<<pgrid, 256, 0, stream>>>(enc, dec, Wq, Wk, Wv, qbuf, kbuf, vT);

    dim3 agrid(T_SZ / 64, NHEADS, B_SZ);
    attn_kernel<<<agrid, 256, 0, stream>>>(qbuf, kbuf, vT, lq1, lq2, lk1, lk2, out);
}

// Round 4
// 406.840 us; speedup vs baseline: 1.1255x; 1.1255x over previous
//
#include <hip/hip_runtime.h>

typedef short bf16x8 __attribute__((ext_vector_type(8)));
typedef float f32x4  __attribute__((ext_vector_type(4)));
typedef unsigned int u32x2 __attribute__((ext_vector_type(2)));

#define B_SZ   2
#define T_SZ   2048
#define N_SZ   2048
#define HID_SZ 1024
#define NHEADS 16

// scale/sqrt(half) * log2(e), folded into Q at projection epilogue
#define SLOG2E 0.25500297f

#define EXP2(x) exp2f(x)

static __device__ __forceinline__ short f2bf(float f) {
    unsigned u = __float_as_uint(f);
    u = (u + 0x7fffu + ((u >> 16) & 1u)) >> 16;   // RNE
    return (short)u;
}

// pack two floats -> two bf16 (round-half-up; 1-ulp tie diff vs RNE)
static __device__ __forceinline__ unsigned pk2(float a, float b) {
    unsigned ua = (__float_as_uint(a) + 0x8000u) >> 16;
    unsigned ub = (__float_as_uint(b) + 0x8000u) & 0xffff0000u;
    return ua | ub;
}

// async global->LDS, 16B per lane; LDS dest = wave-uniform base + lane*16
static __device__ __forceinline__ void gload16(const void* g, void* l) {
    __builtin_amdgcn_global_load_lds(
        (const __attribute__((address_space(1))) unsigned int*)g,
        (__attribute__((address_space(3))) unsigned int*)l, 16, 0, 0);
}

// ---------------------------------------------------------------------------
// fp32 -> bf16 pre-convert (RNE), 8 elem/thread. blockIdx.y selects tensor.
// ---------------------------------------------------------------------------
__global__ __launch_bounds__(256) void cvt_kernel(
    const float* __restrict__ dec, const float* __restrict__ enc,
    const float* __restrict__ Wq, const float* __restrict__ Wk,
    const float* __restrict__ Wv,
    short* __restrict__ decb, short* __restrict__ encb,
    short* __restrict__ wqb, short* __restrict__ wkb, short* __restrict__ wvb)
{
    const float* src; short* dst; int n;
    switch (blockIdx.y) {
      case 0: src = dec; dst = decb; n = B_SZ * T_SZ * HID_SZ; break;
      case 1: src = enc; dst = encb; n = B_SZ * N_SZ * HID_SZ; break;
      case 2: src = Wq;  dst = wqb;  n = HID_SZ * HID_SZ;      break;
      case 3: src = Wk;  dst = wkb;  n = HID_SZ * HID_SZ;      break;
      default:src = Wv;  dst = wvb;  n = HID_SZ * HID_SZ;      break;
    }
    const int idx = (blockIdx.x * 256 + threadIdx.x) * 8;
    if (idx >= n) return;
    float4 a = *(const float4*)&src[idx];
    float4 b = *(const float4*)&src[idx + 4];
    bf16x8 r;
    r[0]=f2bf(a.x); r[1]=f2bf(a.y); r[2]=f2bf(a.z); r[3]=f2bf(a.w);
    r[4]=f2bf(b.x); r[5]=f2bf(b.y); r[6]=f2bf(b.z); r[7]=f2bf(b.w);
    *(bf16x8*)&dst[idx] = r;
}

// ---------------------------------------------------------------------------
// Projection GEMM, m97 structure: bf16 in, bf16 out. 128x128 tile, BK=64,
// 256 thr = 4 waves (2x2), 64x64/wave, global_load_lds 16B staging,
// LDS [128 rows][64 k] row-major (128B rows). 32 MFMA / k-iter / wave.
// 1D grid 768, XCD-swizzled: consecutive slots on an XCD share (proj,c0)
// so the W tile slice stays L2-resident.
// proj 0: q = (dec@Wq^T)*SLOG2E -> qbuf;  proj 1: k -> kbuf
// proj 2: v -> vT [B,H,64,2048], n-permuted: n'=(n&~63)|((n&15)*4+((n>>4)&3))
// ---------------------------------------------------------------------------
__global__ __launch_bounds__(256) void proj_kernel(
    const short* __restrict__ decb, const short* __restrict__ encb,
    const short* __restrict__ wqb, const short* __restrict__ wkb,
    const short* __restrict__ wvb,
    short* __restrict__ qbuf, short* __restrict__ kbuf, short* __restrict__ vT)
{
    const int i    = blockIdx.x;
    const int work = (i & 7) * 96 + (i >> 3);     // XCD-contiguous work id
    const int proj = work >> 8;                   // 256 blocks per projection
    const int rem  = work & 255;
    const int c0   = (rem >> 5) * 128;            // 8 c-tiles (outer on XCD)
    const int m0   = (rem & 31) * 128;            // 32 m-tiles

    const short* __restrict__ X = (proj == 0) ? decb : encb;
    const short* __restrict__ W = (proj == 0) ? wqb : ((proj == 1) ? wkb : wvb);

    __shared__ short As[128 * 64];   // 16 KB
    __shared__ short Bs[128 * 64];   // 16 KB

    const int tid  = threadIdx.x;
    const int lane = tid & 63;
    const int w    = tid >> 6;
    const int wm   = (w >> 1) * 64;
    const int wn   = (w & 1) * 64;
    const int q4   = lane >> 4;
    const int r16  = lane & 15;

    const int srow = w * 32;            // wave stages rows [w*32, w*32+32)
    const int lcol = (lane & 7) * 8;    // k-offset in shorts
    const int lrow = lane >> 3;         // 0..7

    f32x4 acc[4][4] = {};

    for (int k0 = 0; k0 < HID_SZ; k0 += 64) {
        __syncthreads();   // prev iter's ds_reads done before overwrite
#pragma unroll
        for (int j = 0; j < 4; ++j) {
            const int row = srow + j * 8 + lrow;
            gload16(&X[(size_t)(m0 + row) * HID_SZ + k0 + lcol],
                    &As[(srow + j * 8) * 64]);
            gload16(&W[(size_t)(c0 + row) * HID_SZ + k0 + lcol],
                    &Bs[(srow + j * 8) * 64]);
        }
        __syncthreads();   // staging drained (vmcnt(0) before barrier)

#pragma unroll
        for (int kk = 0; kk < 2; ++kk) {
            bf16x8 af[4], bfr[4];
#pragma unroll
            for (int mi = 0; mi < 4; ++mi)
                af[mi] = *(const bf16x8*)&As[(wm + mi * 16 + r16) * 64 + kk * 32 + q4 * 8];
#pragma unroll
            for (int ni = 0; ni < 4; ++ni)
                bfr[ni] = *(const bf16x8*)&Bs[(wn + ni * 16 + r16) * 64 + kk * 32 + q4 * 8];
#pragma unroll
            for (int mi = 0; mi < 4; ++mi)
#pragma unroll
                for (int ni = 0; ni < 4; ++ni)
                    acc[mi][ni] = __builtin_amdgcn_mfma_f32_16x16x32_bf16(
                        af[mi], bfr[ni], acc[mi][ni], 0, 0, 0);
        }
    }

#pragma unroll
    for (int mi = 0; mi < 4; ++mi)
#pragma unroll
    for (int ni = 0; ni < 4; ++ni)
#pragma unroll
    for (int r = 0; r < 4; ++r) {
        const int m = m0 + wm + mi * 16 + q4 * 4 + r;
        const int c = c0 + wn + ni * 16 + r16;
        const float v = acc[mi][ni][r];
        if (proj == 0) {
            qbuf[(size_t)m * HID_SZ + c] = f2bf(v * SLOG2E);
        } else if (proj == 1) {
            kbuf[(size_t)m * HID_SZ + c] = f2bf(v);
        } else {
            const int bb = m >> 11, n = m & (N_SZ - 1);
            const int hh = c >> 6, d = c & 63;
            const int np = (n & ~63) | (((n & 15) << 2) | ((n >> 4) & 3));
            vT[((size_t)((bb * NHEADS + hh) * 64 + d)) * N_SZ + np] = f2bf(v);
        }
    }
}

// ---------------------------------------------------------------------------
// Flash-style differential cross-attention, software-pipelined, no barriers.
// 1D grid 1024, XCD-swizzled: each XCD gets 4 (h,b) groups x 32 t-tiles so
// its K/V slices (~2 MB) + q stay L2-resident -> prefetch covers L2 latency.
// ---------------------------------------------------------------------------
__global__ __launch_bounds__(256) void attn_kernel(
    const short* __restrict__ qbuf, const short* __restrict__ kbuf,
    const short* __restrict__ vT,
    const float* __restrict__ lq1, const float* __restrict__ lq2,
    const float* __restrict__ lk1, const float* __restrict__ lk2,
    float* __restrict__ out)
{
    const int bi   = blockIdx.x;
    const int work = (bi & 7) * 128 + (bi >> 3);   // XCD-contiguous work id
    const int t0   = (work & 31) * 64;             // t fastest within XCD
    const int hb   = work >> 5;
    const int h    = hb & 15;
    const int b    = hb >> 4;

    const int tid = threadIdx.x;
    const int w    = tid >> 6;
    const int lane = tid & 63;
    const int q4   = lane >> 4;
    const int r16  = lane & 15;

    float d1 = 0.f, d2 = 0.f;
#pragma unroll
    for (int i = 0; i < 32; ++i) { d1 += lq1[i] * lk1[i]; d2 += lq2[i] * lk2[i]; }
    const float lam = __expf(d1) - __expf(d2) + 0.8f;

    __shared__ short Pl[4][2 * 16 * 64];
    short* __restrict__ P = &Pl[w][0];

    const int trow = t0 + w * 16 + r16;
    const short* qrow = qbuf + ((size_t)(b * T_SZ + trow)) * HID_SZ + h * 64;
    const bf16x8 aq1 = *(const bf16x8*)(qrow + q4 * 8);
    const bf16x8 aq2 = *(const bf16x8*)(qrow + 32 + q4 * 8);

    const short* kbase = kbuf + (size_t)b * N_SZ * HID_SZ + h * 64;
    const short* vbase = vT + ((size_t)(b * NHEADS + h)) * 64 * N_SZ;

    f32x4 o0[4] = {}, o1[4] = {};
    float l0p[4] = {0.f, 0.f, 0.f, 0.f}, l1p[4] = {0.f, 0.f, 0.f, 0.f};

    const int wg_half = (r16 >> 1);
    const int wlo     = (r16 & 1) * 4;

    // prefetch K chunk 0
    bf16x8 kc1[4], kc2[4];
#pragma unroll
    for (int s = 0; s < 4; ++s) {
        const short* krow = kbase + (size_t)(s * 16 + r16) * HID_SZ;
        kc1[s] = *(const bf16x8*)(krow + q4 * 8);
        kc2[s] = *(const bf16x8*)(krow + 32 + q4 * 8);
    }

    for (int n0 = 0; n0 < N_SZ; n0 += 64) {
        // current-chunk V loads (consumed at PV, ~end of chunk)
        bf16x8 vfr[2][4];
#pragma unroll
        for (int kk = 0; kk < 2; ++kk)
#pragma unroll
            for (int d = 0; d < 4; ++d)
                vfr[kk][d] = *(const bf16x8*)(vbase + (size_t)(d * 16 + r16) * N_SZ
                                              + n0 + kk * 32 + q4 * 8);

        // next-chunk K loads (consumed next iteration)
        bf16x8 kn1[4], kn2[4];
        const int n1 = (n0 + 64) & (N_SZ - 1);
#pragma unroll
        for (int s = 0; s < 4; ++s) {
            const short* krow = kbase + (size_t)(n1 + s * 16 + r16) * HID_SZ;
            kn1[s] = *(const bf16x8*)(krow + q4 * 8);
            kn2[s] = *(const bf16x8*)(krow + 32 + q4 * 8);
        }

        const f32x4 zz = {0.f, 0.f, 0.f, 0.f};
        f32x4 s0[4], s1[4];
#pragma unroll
        for (int s = 0; s < 4; ++s) {
            s0[s] = __builtin_amdgcn_mfma_f32_16x16x32_bf16(aq1, kc1[s], zz, 0, 0, 0);
            s1[s] = __builtin_amdgcn_mfma_f32_16x16x32_bf16(aq2, kc2[s], zz, 0, 0, 0);
        }

        // exp2 + pack + wave-private LDS stage (Q pre-scaled to log2 domain)
#pragma unroll
        for (int r = 0; r < 4; ++r) {
            const int row = q4 * 4 + r;
            const int wo  = row * 64 + ((wg_half ^ (row & 7)) << 3) + wlo;
            {
                float p0 = EXP2(s0[0][r]), p1 = EXP2(s0[1][r]);
                float p2 = EXP2(s0[2][r]), p3 = EXP2(s0[3][r]);
                l0p[r] += (p0 + p1) + (p2 + p3);
                u32x2 pw; pw[0] = pk2(p0, p1); pw[1] = pk2(p2, p3);
                *(u32x2*)&P[wo] = pw;
            }
            {
                float p0 = EXP2(s1[0][r]), p1 = EXP2(s1[1][r]);
                float p2 = EXP2(s1[2][r]), p3 = EXP2(s1[3][r]);
                l1p[r] += (p0 + p1) + (p2 + p3);
                u32x2 pw; pw[0] = pk2(p0, p1); pw[1] = pk2(p2, p3);
                *(u32x2*)&P[1024 + wo] = pw;
            }
        }

        // PV (P via LDS layout transform; V from prefetched regs)
#pragma unroll
        for (int kk = 0; kk < 2; ++kk) {
            const int ro = r16 * 64 + (((kk * 4 + q4) ^ (r16 & 7)) << 3);
            bf16x8 ap0 = *(const bf16x8*)&P[ro];
            bf16x8 ap1 = *(const bf16x8*)&P[1024 + ro];
#pragma unroll
            for (int d = 0; d < 4; ++d) {
                o0[d] = __builtin_amdgcn_mfma_f32_16x16x32_bf16(ap0, vfr[kk][d], o0[d], 0, 0, 0);
                o1[d] = __builtin_amdgcn_mfma_f32_16x16x32_bf16(ap1, vfr[kk][d], o1[d], 0, 0, 0);
            }
        }

#pragma unroll
        for (int s = 0; s < 4; ++s) { kc1[s] = kn1[s]; kc2[s] = kn2[s]; }
    }

#pragma unroll
    for (int m = 1; m < 16; m <<= 1)
#pragma unroll
        for (int r = 0; r < 4; ++r) {
            l0p[r] += __shfl_xor(l0p[r], m);
            l1p[r] += __shfl_xor(l1p[r], m);
        }

    float rl0[4], rl1[4];
#pragma unroll
    for (int r = 0; r < 4; ++r) { rl0[r] = 1.f / l0p[r]; rl1[r] = lam / l1p[r]; }

#pragma unroll
    for (int d = 0; d < 4; ++d)
#pragma unroll
        for (int r = 0; r < 4; ++r) {
            const int t  = t0 + w * 16 + q4 * 4 + r;
            const int vd = d * 16 + r16;
            out[((size_t)(b * T_SZ + t)) * HID_SZ + h * 64 + vd] =
                o0[d][r] * rl0[r] - o1[d][r] * rl1[r];
        }
}

extern "C" void kernel_launch(void* const* d_in, const int* in_sizes, int n_in,
                              void* d_out, int out_size, void* d_ws, size_t ws_size,
                              hipStream_t stream)
{
    (void)in_sizes; (void)n_in; (void)out_size; (void)ws_size;

    const float* enc = (const float*)d_in[0];
    const float* dec = (const float*)d_in[1];
    const float* Wq  = (const float*)d_in[2];
    const float* Wk  = (const float*)d_in[3];
    const float* Wv  = (const float*)d_in[4];
    const float* lq1 = (const float*)d_in[5];
    const float* lq2 = (const float*)d_in[6];
    const float* lk1 = (const float*)d_in[7];
    const float* lk2 = (const float*)d_in[8];
    float* out = (float*)d_out;

    short* qbuf = (short*)d_ws;                          // [4096,1024]
    short* kbuf = qbuf + (size_t)4096 * 1024;            // [4096,1024]
    short* vT   = kbuf + (size_t)4096 * 1024;            // [B,H,64,2048]
    short* decb = vT   + (size_t)4096 * 1024;            // [2,2048,1024]
    short* encb = decb + (size_t)2 * 2048 * 1024;        // [2,2048,1024]
    short* wqb  = encb + (size_t)2 * 2048 * 1024;        // [1024,1024]
    short* wkb  = wqb  + (size_t)1024 * 1024;
    short* wvb  = wkb  + (size_t)1024 * 1024;

    cvt_kernel<<<dim3(2048, 5), 256, 0, stream>>>(
        dec, enc, Wq, Wk, Wv, decb, encb, wqb, wkb, wvb);

    proj_kernel<<<768, 256, 0, stream>>>(
        decb, encb, wqb, wkb, wvb, qbuf, kbuf, vT);

    attn_kernel<<<1024, 256, 0, stream>>>(
        qbuf, kbuf, vT, lq1, lq2, lk1, lk2, out);
}